// Round 4
// baseline (224.172 us; speedup 1.0000x reference)
//
#include <hip/hip_runtime.h>
#include <hip/hip_bf16.h>
#include <math.h>
#include <stdint.h>

// Problem constants (from reference)
//   inputs  [64, 512, 32, 32] f32
//   W_route [512,16], b_route [16], W_noise [512,16], b_noise [16]
//   A_logs  [16, 2048, 32] f32
//   out: combined [2048,32] f32 (65536) ++ z_loss (1)  => 65537 f32
//
// R2 lesson: device-scope ticket/spin fusion cost 94-156us (cross-XCD flag
// polling). Kernel boundaries are the cheap sync (~2us).
// R3 lesson: 3-kernel structure validated bit-exact at 215us headline.
// R4 change: K1 loads are PLAIN (not nontemporal) — the harness's d_in
// restore copy should leave `inputs` Infinity-Cache-resident (128 MiB < 256
// MiB L3), and the nt flag was forcing the HBM path. Everything else is
// byte-identical to R3.

typedef float fvec4 __attribute__((ext_vector_type(4)));

// ---------------------------------------------------------------------------
// K1: spatial mean pool. One 64-lane wave per (b,c) row of 1024 contiguous
// floats. Plain float4 loads (L3-warm data — let it hit Infinity Cache).
// rows = 64*512 = 32768; 4 waves/block -> 8192 blocks x 256 threads exactly.
// ---------------------------------------------------------------------------
__global__ __launch_bounds__(256) void k_meanpool(const float* __restrict__ in,
                                                  float* __restrict__ x) {
  int gwave = (blockIdx.x * 256 + threadIdx.x) >> 6;   // (b*512 + c)
  int lane  = threadIdx.x & 63;
  const fvec4* p = reinterpret_cast<const fvec4*>(in) + (size_t)gwave * 256;
  float s = 0.f;
#pragma unroll
  for (int j = 0; j < 4; ++j) {
    fvec4 v = p[lane + 64 * j];
    s += (v.x + v.y) + (v.z + v.w);
  }
#pragma unroll
  for (int off = 32; off > 0; off >>= 1) s += __shfl_down(s, off, 64);
  if (lane == 0) x[gwave] = s * (1.0f / 1024.0f);
}

// ---------------------------------------------------------------------------
// JAX Threefry-2x32, exact port of jax/_src/prng.py (key = (0, 42)).
// ---------------------------------------------------------------------------
__device__ __forceinline__ uint32_t rotl32(uint32_t v, int d) {
  return (v << d) | (v >> (32 - d));
}

__device__ __forceinline__ void threefry2x32_0_42(uint32_t& x0, uint32_t& x1) {
  const uint32_t k0 = 0u, k1 = 42u;
  const uint32_t ks2 = k0 ^ k1 ^ 0x1BD11BDAu;
  x0 += k0; x1 += k1;
#define RND(rot) { x0 += x1; x1 = rotl32(x1, rot); x1 ^= x0; }
#define G4(a,b,c,d, ka,kb,inc) { RND(a) RND(b) RND(c) RND(d) x0 += ka; x1 += kb + inc; }
  G4(13,15,26,6,  k1,  ks2, 1u)
  G4(17,29,16,24, ks2, k0,  2u)
  G4(13,15,26,6,  k0,  k1,  3u)
  G4(17,29,16,24, k1,  ks2, 4u)
  G4(13,15,26,6,  ks2, k0,  5u)
#undef G4
#undef RND
}

// erfinv f32 — Giles polynomial, exactly what XLA lowers lax.erf_inv to.
__device__ __forceinline__ float erfinv_f32(float x) {
  float w = -log1pf(-x * x);
  float p;
  if (w < 5.0f) {
    w -= 2.5f;
    p = 2.81022636e-08f;
    p = fmaf(p, w, 3.43273939e-07f);
    p = fmaf(p, w, -3.5233877e-06f);
    p = fmaf(p, w, -4.39150654e-06f);
    p = fmaf(p, w, 0.00021858087f);
    p = fmaf(p, w, -0.00125372503f);
    p = fmaf(p, w, -0.00417768164f);
    p = fmaf(p, w, 0.246640727f);
    p = fmaf(p, w, 1.50140941f);
  } else {
    w = sqrtf(w) - 3.0f;
    p = -0.000200214257f;
    p = fmaf(p, w, 0.000100950558f);
    p = fmaf(p, w, 0.00134934322f);
    p = fmaf(p, w, -0.00367342844f);
    p = fmaf(p, w, 0.00573950773f);
    p = fmaf(p, w, -0.0076224613f);
    p = fmaf(p, w, 0.00943887047f);
    p = fmaf(p, w, 1.00167406f);
    p = fmaf(p, w, 2.83297682f);
  }
  return p * x;
}

// ---------------------------------------------------------------------------
// K2: per-batch-row router (identical math/order to the bit-exact R1 kernel).
// Block b: stage x[b,:] in LDS, 256 threads split the two 512x16 GEMVs,
// 16 threads do threefry/erfinv/softplus/softmaxes, thread 0 does top-2.
// Outputs: idx[64*2], rw[64*2], lse[64] in ws (plain stores; the kernel
// boundary makes them visible to K3).
// ---------------------------------------------------------------------------
__global__ __launch_bounds__(256) void k_router(
    const float* __restrict__ x,
    const float* __restrict__ Wr, const float* __restrict__ br,
    const float* __restrict__ Wn, const float* __restrict__ bn,
    int* __restrict__ idx, float* __restrict__ rw, float* __restrict__ lseArr) {
  __shared__ float xs[512];
  __shared__ float pr[16][17], pn[16][17];   // +1 pad: no bank conflicts
  __shared__ float lg[16], npre[16], noisy[16];
  const int b = blockIdx.x, tid = threadIdx.x;

  for (int d = tid; d < 512; d += 256) xs[d] = x[b * 512 + d];
  __syncthreads();

  const int e = tid & 15, c = tid >> 4;
  float sr = 0.f, sn = 0.f;
#pragma unroll 8
  for (int j = 0; j < 32; ++j) {
    int d = c * 32 + j;
    float xv = xs[d];
    sr = fmaf(xv, Wr[d * 16 + e], sr);
    sn = fmaf(xv, Wn[d * 16 + e], sn);
  }
  pr[c][e] = sr;
  pn[c][e] = sn;
  __syncthreads();

  if (tid < 16) {
    float a = 0.f, bb = 0.f;
    for (int cc = 0; cc < 16; ++cc) { a += pr[cc][tid]; bb += pn[cc][tid]; }
    lg[tid] = a + br[tid];
    float v = bb + bn[tid];
    // eps = jax.random.normal(key(42), [64,16])[b, tid]
    uint32_t i  = (uint32_t)(b * 16 + tid);     // row-major element index
    uint32_t j  = i & 511u;                     // pair index
    uint32_t x0 = j, x1 = j + 512u;             // iota halves
    threefry2x32_0_42(x0, x1);
    uint32_t bits = (i < 512u) ? x0 : x1;
    float u01 = __uint_as_float((bits >> 9) | 0x3f800000u) - 1.0f;
    const float lo = -0.99999994f;              // nextafter(-1, 0)
    float u = fmaf(u01, 1.0f - lo, lo);
    u = fmaxf(lo, u);
    float eps = 1.41421356f * erfinv_f32(u);    // f32(sqrt(2)) * erfinv(u)
    // softplus = logaddexp(v, 0)
    float sp = fmaxf(v, 0.f) + log1pf(expf(-fabsf(v)));
    npre[tid] = eps * sp;
  }
  __syncthreads();

  if (tid < 16) {
    float ml = -INFINITY, mn = -INFINITY;
    for (int q = 0; q < 16; ++q) { ml = fmaxf(ml, lg[q]); mn = fmaxf(mn, npre[q]); }
    float sl = 0.f, sn2 = 0.f;
    for (int q = 0; q < 16; ++q) { sl += expf(lg[q] - ml); sn2 += expf(npre[q] - mn); }
    noisy[tid] = expf(lg[tid] - ml) / sl + expf(npre[tid] - mn) / sn2;
  }
  __syncthreads();

  if (tid == 0) {
    // top-2 with jax.lax.top_k tie-break (first occurrence wins)
    int i0 = 0; float v0 = noisy[0];
    for (int q = 1; q < 16; ++q) if (noisy[q] > v0) { v0 = noisy[q]; i0 = q; }
    int i1 = -1; float v1 = -INFINITY;
    for (int q = 0; q < 16; ++q) {
      if (q == i0) continue;
      if (noisy[q] > v1) { v1 = noisy[q]; i1 = q; }
    }
    float t = expf(v1 - v0);
    float inv = 1.0f / (1.0f + t);
    idx[b * 2 + 0] = i0; idx[b * 2 + 1] = i1;
    rw [b * 2 + 0] = inv; rw [b * 2 + 1] = t * inv;
    // logsumexp(noisy)
    float m = -INFINITY;
    for (int q = 0; q < 16; ++q) m = fmaxf(m, noisy[q]);
    float s2 = 0.f;
    for (int q = 0; q < 16; ++q) s2 += expf(noisy[q] - m);
    lseArr[b] = m + logf(s2);
  }
}

// ---------------------------------------------------------------------------
// K3: combine + redundant per-block w-reduce. Each of the 64 blocks
// recomputes w[16] from idx/rw (1.2 KB, L2-hot) with the EXACT same loop
// order as the validated k_reduce -> bit-identical w in every block, fully
// deterministic across graph replays. Block 0 additionally writes z_loss.
// Then each block combines its 256-float4 slice (identical FP order to the
// validated k_combine).
// ---------------------------------------------------------------------------
__global__ __launch_bounds__(256) void k_combine(const float* __restrict__ A,
                                                 const int* __restrict__ idx,
                                                 const float* __restrict__ rw,
                                                 const float* __restrict__ lse,
                                                 float* __restrict__ out) {
  __shared__ int   sIdx[128];
  __shared__ float sRw[128];
  __shared__ float wsm[16];
  const int b = blockIdx.x, tid = threadIdx.x;

  if (tid < 128) { sIdx[tid] = idx[tid]; sRw[tid] = rw[tid]; }
  __syncthreads();

  if (tid < 16) {
    float acc = 0.f;
    for (int j = 0; j < 128; ++j)
      if (sIdx[j] == tid) acc += sRw[j];
    wsm[tid] = acc * (1.0f / 64.0f);   // mean over batch folded into weight
  }
  if (b == 0 && tid == 32) {
    float z = 0.f;
    for (int q = 0; q < 64; ++q) { float l = lse[q]; z += l * l; }
    out[65536] = z * (1.0f / 64.0f);   // z_loss
  }
  __syncthreads();

  float wl[16];
#pragma unroll
  for (int e = 0; e < 16; ++e) wl[e] = wsm[e];

  int t = b * 256 + tid;               // 0..16383 (float4 index)
  const float4* A4 = reinterpret_cast<const float4*>(A);
  float4 acc = make_float4(0.f, 0.f, 0.f, 0.f);
#pragma unroll
  for (int e = 0; e < 16; ++e) {
    float we = wl[e];
    float4 v = A4[e * 16384 + t];
    acc.x = fmaf(we, v.x, acc.x);
    acc.y = fmaf(we, v.y, acc.y);
    acc.z = fmaf(we, v.z, acc.z);
    acc.w = fmaf(we, v.w, acc.w);
  }
  reinterpret_cast<float4*>(out)[t] = acc;
}

// ---------------------------------------------------------------------------
extern "C" void kernel_launch(void* const* d_in, const int* in_sizes, int n_in,
                              void* d_out, int out_size, void* d_ws, size_t ws_size,
                              hipStream_t stream) {
  const float* inputs = (const float*)d_in[0];  // [64,512,32,32]
  const float* Wr     = (const float*)d_in[1];  // [512,16]
  const float* br     = (const float*)d_in[2];  // [16]
  const float* Wn     = (const float*)d_in[3];  // [512,16]
  const float* bn     = (const float*)d_in[4];  // [16]
  const float* A      = (const float*)d_in[5];  // [16,2048,32]
  float* out = (float*)d_out;                   // 65536 combined + 1 z_loss

  char* ws   = (char*)d_ws;                     // 0xAA-poisoned every launch
  float* x   = (float*)(ws);                    // [64,512]  131072 B
  int*   idx = (int*)  (ws + 131072);           // [64,2]       512 B
  float* rw  = (float*)(ws + 131584);           // [64,2]       512 B
  float* lse = (float*)(ws + 132096);           // [64]         256 B

  hipLaunchKernelGGL(k_meanpool, dim3(8192), dim3(256), 0, stream, inputs, x);
  hipLaunchKernelGGL(k_router,   dim3(64),   dim3(256), 0, stream, x, Wr, br, Wn, bn, idx, rw, lse);
  hipLaunchKernelGGL(k_combine,  dim3(64),   dim3(256), 0, stream, A, idx, rw, lse, out);
}

// Round 5
// 212.041 us; speedup vs baseline: 1.0572x; 1.0572x over previous
//
#include <hip/hip_runtime.h>
#include <hip/hip_bf16.h>
#include <math.h>
#include <stdint.h>

// Problem constants (from reference)
//   inputs  [64, 512, 32, 32] f32
//   W_route [512,16], b_route [16], W_noise [512,16], b_noise [16]
//   A_logs  [16, 2048, 32] f32
//   out: combined [2048,32] f32 (65536) ++ z_loss (1)  => 65537 f32
//
// R2 lesson: device-scope ticket/spin fusion cost 94-156us (cross-XCD flag
// polling). Kernel boundaries are the cheap sync (~2us).
// R3 lesson: 3-kernel structure, NT loads in K1: 215us headline (best).
// R4 lesson: plain (cache-allocating) loads in K1 cost +9us — the harness's
// 512MB poison fills evict d_in from L3 between restore and launch; treat
// d_in as L3-cold and stream it nontemporally.
// R5: byte-for-byte revert to the R3 configuration.

typedef float fvec4 __attribute__((ext_vector_type(4)));

// ---------------------------------------------------------------------------
// K1: spatial mean pool. One 64-lane wave per (b,c) row of 1024 contiguous
// floats. Nontemporal float4 loads (stream-once data, skip cache allocate).
// rows = 64*512 = 32768; 4 waves/block -> 8192 blocks x 256 threads exactly.
// ---------------------------------------------------------------------------
__global__ __launch_bounds__(256) void k_meanpool(const float* __restrict__ in,
                                                  float* __restrict__ x) {
  int gwave = (blockIdx.x * 256 + threadIdx.x) >> 6;   // (b*512 + c)
  int lane  = threadIdx.x & 63;
  const fvec4* p = reinterpret_cast<const fvec4*>(in) + (size_t)gwave * 256;
  float s = 0.f;
#pragma unroll
  for (int j = 0; j < 4; ++j) {
    fvec4 v = __builtin_nontemporal_load(&p[lane + 64 * j]);
    s += (v.x + v.y) + (v.z + v.w);
  }
#pragma unroll
  for (int off = 32; off > 0; off >>= 1) s += __shfl_down(s, off, 64);
  if (lane == 0) x[gwave] = s * (1.0f / 1024.0f);
}

// ---------------------------------------------------------------------------
// JAX Threefry-2x32, exact port of jax/_src/prng.py (key = (0, 42)).
// ---------------------------------------------------------------------------
__device__ __forceinline__ uint32_t rotl32(uint32_t v, int d) {
  return (v << d) | (v >> (32 - d));
}

__device__ __forceinline__ void threefry2x32_0_42(uint32_t& x0, uint32_t& x1) {
  const uint32_t k0 = 0u, k1 = 42u;
  const uint32_t ks2 = k0 ^ k1 ^ 0x1BD11BDAu;
  x0 += k0; x1 += k1;
#define RND(rot) { x0 += x1; x1 = rotl32(x1, rot); x1 ^= x0; }
#define G4(a,b,c,d, ka,kb,inc) { RND(a) RND(b) RND(c) RND(d) x0 += ka; x1 += kb + inc; }
  G4(13,15,26,6,  k1,  ks2, 1u)
  G4(17,29,16,24, ks2, k0,  2u)
  G4(13,15,26,6,  k0,  k1,  3u)
  G4(17,29,16,24, k1,  ks2, 4u)
  G4(13,15,26,6,  ks2, k0,  5u)
#undef G4
#undef RND
}

// erfinv f32 — Giles polynomial, exactly what XLA lowers lax.erf_inv to.
__device__ __forceinline__ float erfinv_f32(float x) {
  float w = -log1pf(-x * x);
  float p;
  if (w < 5.0f) {
    w -= 2.5f;
    p = 2.81022636e-08f;
    p = fmaf(p, w, 3.43273939e-07f);
    p = fmaf(p, w, -3.5233877e-06f);
    p = fmaf(p, w, -4.39150654e-06f);
    p = fmaf(p, w, 0.00021858087f);
    p = fmaf(p, w, -0.00125372503f);
    p = fmaf(p, w, -0.00417768164f);
    p = fmaf(p, w, 0.246640727f);
    p = fmaf(p, w, 1.50140941f);
  } else {
    w = sqrtf(w) - 3.0f;
    p = -0.000200214257f;
    p = fmaf(p, w, 0.000100950558f);
    p = fmaf(p, w, 0.00134934322f);
    p = fmaf(p, w, -0.00367342844f);
    p = fmaf(p, w, 0.00573950773f);
    p = fmaf(p, w, -0.0076224613f);
    p = fmaf(p, w, 0.00943887047f);
    p = fmaf(p, w, 1.00167406f);
    p = fmaf(p, w, 2.83297682f);
  }
  return p * x;
}

// ---------------------------------------------------------------------------
// K2: per-batch-row router (identical math/order to the bit-exact R1 kernel).
// Block b: stage x[b,:] in LDS, 256 threads split the two 512x16 GEMVs,
// 16 threads do threefry/erfinv/softplus/softmaxes, thread 0 does top-2.
// Outputs: idx[64*2], rw[64*2], lse[64] in ws (plain stores; the kernel
// boundary makes them visible to K3).
// ---------------------------------------------------------------------------
__global__ __launch_bounds__(256) void k_router(
    const float* __restrict__ x,
    const float* __restrict__ Wr, const float* __restrict__ br,
    const float* __restrict__ Wn, const float* __restrict__ bn,
    int* __restrict__ idx, float* __restrict__ rw, float* __restrict__ lseArr) {
  __shared__ float xs[512];
  __shared__ float pr[16][17], pn[16][17];   // +1 pad: no bank conflicts
  __shared__ float lg[16], npre[16], noisy[16];
  const int b = blockIdx.x, tid = threadIdx.x;

  for (int d = tid; d < 512; d += 256) xs[d] = x[b * 512 + d];
  __syncthreads();

  const int e = tid & 15, c = tid >> 4;
  float sr = 0.f, sn = 0.f;
#pragma unroll 8
  for (int j = 0; j < 32; ++j) {
    int d = c * 32 + j;
    float xv = xs[d];
    sr = fmaf(xv, Wr[d * 16 + e], sr);
    sn = fmaf(xv, Wn[d * 16 + e], sn);
  }
  pr[c][e] = sr;
  pn[c][e] = sn;
  __syncthreads();

  if (tid < 16) {
    float a = 0.f, bb = 0.f;
    for (int cc = 0; cc < 16; ++cc) { a += pr[cc][tid]; bb += pn[cc][tid]; }
    lg[tid] = a + br[tid];
    float v = bb + bn[tid];
    // eps = jax.random.normal(key(42), [64,16])[b, tid]
    uint32_t i  = (uint32_t)(b * 16 + tid);     // row-major element index
    uint32_t j  = i & 511u;                     // pair index
    uint32_t x0 = j, x1 = j + 512u;             // iota halves
    threefry2x32_0_42(x0, x1);
    uint32_t bits = (i < 512u) ? x0 : x1;
    float u01 = __uint_as_float((bits >> 9) | 0x3f800000u) - 1.0f;
    const float lo = -0.99999994f;              // nextafter(-1, 0)
    float u = fmaf(u01, 1.0f - lo, lo);
    u = fmaxf(lo, u);
    float eps = 1.41421356f * erfinv_f32(u);    // f32(sqrt(2)) * erfinv(u)
    // softplus = logaddexp(v, 0)
    float sp = fmaxf(v, 0.f) + log1pf(expf(-fabsf(v)));
    npre[tid] = eps * sp;
  }
  __syncthreads();

  if (tid < 16) {
    float ml = -INFINITY, mn = -INFINITY;
    for (int q = 0; q < 16; ++q) { ml = fmaxf(ml, lg[q]); mn = fmaxf(mn, npre[q]); }
    float sl = 0.f, sn2 = 0.f;
    for (int q = 0; q < 16; ++q) { sl += expf(lg[q] - ml); sn2 += expf(npre[q] - mn); }
    noisy[tid] = expf(lg[tid] - ml) / sl + expf(npre[tid] - mn) / sn2;
  }
  __syncthreads();

  if (tid == 0) {
    // top-2 with jax.lax.top_k tie-break (first occurrence wins)
    int i0 = 0; float v0 = noisy[0];
    for (int q = 1; q < 16; ++q) if (noisy[q] > v0) { v0 = noisy[q]; i0 = q; }
    int i1 = -1; float v1 = -INFINITY;
    for (int q = 0; q < 16; ++q) {
      if (q == i0) continue;
      if (noisy[q] > v1) { v1 = noisy[q]; i1 = q; }
    }
    float t = expf(v1 - v0);
    float inv = 1.0f / (1.0f + t);
    idx[b * 2 + 0] = i0; idx[b * 2 + 1] = i1;
    rw [b * 2 + 0] = inv; rw [b * 2 + 1] = t * inv;
    // logsumexp(noisy)
    float m = -INFINITY;
    for (int q = 0; q < 16; ++q) m = fmaxf(m, noisy[q]);
    float s2 = 0.f;
    for (int q = 0; q < 16; ++q) s2 += expf(noisy[q] - m);
    lseArr[b] = m + logf(s2);
  }
}

// ---------------------------------------------------------------------------
// K3: combine + redundant per-block w-reduce. Each of the 64 blocks
// recomputes w[16] from idx/rw (1.2 KB, L2-hot) with the EXACT same loop
// order as the validated k_reduce -> bit-identical w in every block, fully
// deterministic across graph replays. Block 0 additionally writes z_loss.
// Then each block combines its 256-float4 slice (identical FP order to the
// validated k_combine).
// ---------------------------------------------------------------------------
__global__ __launch_bounds__(256) void k_combine(const float* __restrict__ A,
                                                 const int* __restrict__ idx,
                                                 const float* __restrict__ rw,
                                                 const float* __restrict__ lse,
                                                 float* __restrict__ out) {
  __shared__ int   sIdx[128];
  __shared__ float sRw[128];
  __shared__ float wsm[16];
  const int b = blockIdx.x, tid = threadIdx.x;

  if (tid < 128) { sIdx[tid] = idx[tid]; sRw[tid] = rw[tid]; }
  __syncthreads();

  if (tid < 16) {
    float acc = 0.f;
    for (int j = 0; j < 128; ++j)
      if (sIdx[j] == tid) acc += sRw[j];
    wsm[tid] = acc * (1.0f / 64.0f);   // mean over batch folded into weight
  }
  if (b == 0 && tid == 32) {
    float z = 0.f;
    for (int q = 0; q < 64; ++q) { float l = lse[q]; z += l * l; }
    out[65536] = z * (1.0f / 64.0f);   // z_loss
  }
  __syncthreads();

  float wl[16];
#pragma unroll
  for (int e = 0; e < 16; ++e) wl[e] = wsm[e];

  int t = b * 256 + tid;               // 0..16383 (float4 index)
  const float4* A4 = reinterpret_cast<const float4*>(A);
  float4 acc = make_float4(0.f, 0.f, 0.f, 0.f);
#pragma unroll
  for (int e = 0; e < 16; ++e) {
    float we = wl[e];
    float4 v = A4[e * 16384 + t];
    acc.x = fmaf(we, v.x, acc.x);
    acc.y = fmaf(we, v.y, acc.y);
    acc.z = fmaf(we, v.z, acc.z);
    acc.w = fmaf(we, v.w, acc.w);
  }
  reinterpret_cast<float4*>(out)[t] = acc;
}

// ---------------------------------------------------------------------------
extern "C" void kernel_launch(void* const* d_in, const int* in_sizes, int n_in,
                              void* d_out, int out_size, void* d_ws, size_t ws_size,
                              hipStream_t stream) {
  const float* inputs = (const float*)d_in[0];  // [64,512,32,32]
  const float* Wr     = (const float*)d_in[1];  // [512,16]
  const float* br     = (const float*)d_in[2];  // [16]
  const float* Wn     = (const float*)d_in[3];  // [512,16]
  const float* bn     = (const float*)d_in[4];  // [16]
  const float* A      = (const float*)d_in[5];  // [16,2048,32]
  float* out = (float*)d_out;                   // 65536 combined + 1 z_loss

  char* ws   = (char*)d_ws;                     // 0xAA-poisoned every launch
  float* x   = (float*)(ws);                    // [64,512]  131072 B
  int*   idx = (int*)  (ws + 131072);           // [64,2]       512 B
  float* rw  = (float*)(ws + 131584);           // [64,2]       512 B
  float* lse = (float*)(ws + 132096);           // [64]         256 B

  hipLaunchKernelGGL(k_meanpool, dim3(8192), dim3(256), 0, stream, inputs, x);
  hipLaunchKernelGGL(k_router,   dim3(64),   dim3(256), 0, stream, x, Wr, br, Wn, bn, idx, rw, lse);
  hipLaunchKernelGGL(k_combine,  dim3(64),   dim3(256), 0, stream, A, idx, rw, lse, out);
}